// Round 16
// baseline (425.941 us; speedup 1.0000x reference)
//
#include <hip/hip_runtime.h>

typedef __attribute__((ext_vector_type(8))) short short8;
typedef __attribute__((ext_vector_type(4))) float f32x4;

#define B_    8
#define CI    256
#define CO    256
#define Hh    160
#define Ww    160
#define HP    162
#define WP    162
#define HWp   (Hh * Ww)                 // 25600
#define XPAD_ELEMS (B_ * HP * WP * CI)  // 53,747,712 bf16
#define W2_ELEMS   (9 * CI * CO)        // 589,824 bf16 (plain [sh][co][ci])
#define NT    36                        // 4 ci-chunks x 9 shifts, BK=64
#define ASL   16384                     // shorts per A slot (256co x 64ci = 32KB)
#define BSL   16384                     // shorts per B slot (256px x 64ci = 32KB)

// fused prep grid partition
#define NBORD 644
#define NPW   2304
#define NPX   (B_ * Hh * 4 * 3)        // 15360

__device__ __forceinline__ unsigned short f2bf(float f) {
  unsigned int u = __float_as_uint(f);
  u += 0x7FFFu + ((u >> 16) & 1u);   // RNE
  return (unsigned short)(u >> 16);
}

// One launch: zero xp border | weight->w2 [sh][co][ci] bf16 | ori*mask->xp NHWC bf16
__global__ void prep_all(const float* __restrict__ ori, const int* __restrict__ mask,
                         const float* __restrict__ w,
                         unsigned short* __restrict__ xp, unsigned short* __restrict__ w2) {
  __shared__ float tile[64][65];
  const int bid = blockIdx.x;
  const int t = threadIdx.x;

  if (bid < NBORD) {
    int g = bid * 256 + t;
    int pos = g >> 5;
    int c = (g & 31) << 3;
    int n = pos / 644;
    int p = pos - n * 644;
    int y, x;
    if (p < 324) { y = (p < 162) ? 0 : 161; x = (p < 162) ? p : p - 162; }
    else { int q = p - 324; y = 1 + (q >> 1); x = (q & 1) ? 161 : 0; }
    unsigned short* d = xp + (((size_t)(n * 162 + y)) * 162 + x) * 256 + c;
    *(uint4*)d = (uint4){0u, 0u, 0u, 0u};
    return;
  }
  if (bid < NBORD + NPW) {
    int i = (bid - NBORD) * 256 + t;     // i = (s*256+co)*256+ci
    int ci = i & 255;
    int t2 = i >> 8;
    int co = t2 & 255;
    int s = t2 >> 8;
    w2[i] = f2bf(w[(co * 256 + ci) * 9 + s]);
    return;
  }

  int bid2 = bid - (NBORD + NPW);        // ((n*160+h)*4+cit)*3+wt
  int wt = bid2 % 3;
  int t1 = bid2 / 3;
  int cit = t1 & 3;
  int t2 = t1 >> 2;
  int h = t2 % Hh;
  int n = t2 / Hh;

  int wl = t & 63;
  int ww = wt * 64 + wl;
  bool valid = (ww < Ww);
  float m = 0.f;
  if (valid) m = (float)mask[(n * Hh + h) * Ww + ww];
  const float* src = ori + (((size_t)(n * CI + cit * 64) * Hh + h) * Ww + ww);
  int r0 = t >> 6;
#pragma unroll
  for (int k = 0; k < 16; ++k) {
    int ci_l = r0 * 16 + k;
    float v = 0.f;
    if (valid) v = src[(size_t)ci_l * HWp] * m;
    tile[ci_l][wl] = v;
  }
  __syncthreads();

  int wl2 = t >> 2;
  int wo = wt * 64 + wl2;
  if (wo < Ww) {
    int cseg = (t & 3) * 16;
    union { unsigned short u[8]; uint4 v; } p0, p1;
#pragma unroll
    for (int j = 0; j < 8; ++j) p0.u[j] = f2bf(tile[cseg + j][wl2]);
#pragma unroll
    for (int j = 0; j < 8; ++j) p1.u[j] = f2bf(tile[cseg + 8 + j][wl2]);
    unsigned short* dst = xp + ((size_t)((n * HP + h + 1) * WP) + (wo + 1)) * CI + cit * 64 + cseg;
    *(uint4*)dst = p0.v;
    *(uint4*)(dst + 8) = p1.v;
  }
}

__device__ __forceinline__ void gload16(const unsigned short* g, unsigned short* l) {
  __builtin_amdgcn_global_load_lds((const __attribute__((address_space(1))) void*)g,
                                   (__attribute__((address_space(3))) void*)l, 16, 0, 0);
}

// m201-geometry implicit GEMM: BM=256co x BN=256px, BK=64, 512 thr = 8 waves
// (2M x 4N), wave 128co x 64px, acc[8][4] f32x4. Both operands in LDS:
// A ring 3x32KB + B dbuf 2x32KB = 160KB, 1 block/CU, grid 800 (8img x 100pxt).
// Per tile 4 quadrant-phases (m0n0,m0n1,m1n1,m1n0 — neighbors share a kept
// operand): reads 12/4/8/4 b128, 16 MFMA each, 2 gloads staged per phase
// (B(t+1) ph1-2 -> Bs[(t+1)&1]; A(t+2) ph3-4 -> As[(t+2)%3]); ONE vmcnt(4)
// per tile (drains B(t+1),A(t+1); keeps A(t+2) flying — never 0 mid-loop).
__global__ void __launch_bounds__(512, 2)
sconv_gemm(const unsigned short* __restrict__ xp, const unsigned short* __restrict__ w2,
           const float* __restrict__ bias, float* __restrict__ out) {
  __shared__ unsigned short As[3 * ASL];   // 96KB
  __shared__ unsigned short Bs[2 * BSL];   // 64KB

  const int bid = blockIdx.x;
  const int n = bid & 7;            // image per XCD
  const int pxt = bid >> 3;         // 0..99
  const int p0 = pxt * 256;

  const int t = threadIdx.x;
  const int l = t & 63;
  const int wv = t >> 6;            // 8 waves
  const int wm = wv >> 2;           // co half (128)
  const int wn = wv & 3;            // px quarter (64)

  const int lr = l >> 3;
  const int swz8 = ((l & 7) ^ lr) << 3;   // proven source pre-swizzle
  const int lc = l & 15, hi4 = l >> 4, lx7 = l & 7;

  // A stage: granules gr = wv*4 + part*2 + j cover co rows [wv*32, wv*32+32)
  const unsigned awoff = (unsigned)(wv * 32 + lr) * 256 + swz8;
  // B stage: same granule scheme over px rows (div/mod per granule)
  unsigned boffB[4];
#pragma unroll
  for (int g = 0; g < 4; ++g) {
    int p = p0 + wv * 32 + g * 8 + lr;
    int h = p / Ww;
    int w = p - h * Ww;
    boffB[g] = (unsigned)((n * HP + h) * WP + w) * 256 + swz8;
  }

  const int abase = (wm * 128 + lc) * 64;
  const int bbase = (wn * 64 + lc) * 64;
  const int sA0 = ((0 + hi4) ^ lx7) << 3;   // kk=0 slot
  const int sA1 = ((4 + hi4) ^ lx7) << 3;   // kk=1 slot

  f32x4 acc[8][4];
#pragma unroll
  for (int j = 0; j < 8; ++j)
#pragma unroll
    for (int i = 0; i < 4; ++i)
      acc[j][i] = (f32x4){0.f, 0.f, 0.f, 0.f};

  short8 aa[8], bb0[4], bb1[4];

#define TPAR(ts, cic, sh, kh, kw)                                             \
  const int cic = ((ts) * 57) >> 9;                                           \
  const int sh = (ts) - cic * 9;                                              \
  const int kh = (sh * 11) >> 5;                                              \
  const int kw = sh - kh * 3;

#define ASTG(ts, SLOT, part) do {                                             \
  TPAR(ts, cic_, sh_, kh_, kw_) (void)kh_; (void)kw_;                         \
  const unsigned short* base_ = w2 + sh_ * 65536 + (cic_ << 6) + awoff;       \
  unsigned short* dst_ = As + (SLOT) * ASL + wv * 2048 + (part) * 1024;       \
  gload16(base_ + (part) * 4096, dst_);                                       \
  gload16(base_ + (part) * 4096 + 2048, dst_ + 512);                          \
} while (0)

#define BSTG(ts, BIDX, part) do {                                             \
  TPAR(ts, cic_, sh_, kh_, kw_)                                               \
  const unsigned bd_ = (unsigned)(kh_ * WP + kw_) * 256 + (cic_ << 6);        \
  unsigned short* dst_ = Bs + (BIDX) * BSL + wv * 2048 + (part) * 1024;       \
  gload16(xp + bd_ + boffB[(part) * 2], dst_);                                \
  gload16(xp + bd_ + boffB[(part) * 2 + 1], dst_ + 512);                      \
} while (0)

#define BBA(mh, AC) do {                                                      \
  _Pragma("unroll")                                                           \
  for (int mf = 0; mf < 4; ++mf) {                                            \
    aa[mf]     = *(const short8*)((AC) + abase + ((mh)*4+mf)*1024 + sA0);     \
    aa[4 + mf] = *(const short8*)((AC) + abase + ((mh)*4+mf)*1024 + sA1);     \
  }                                                                           \
} while (0)

#define BBB(nh, bb, BC) do {                                                  \
  _Pragma("unroll")                                                           \
  for (int nf = 0; nf < 2; ++nf) {                                            \
    bb[nf]     = *(const short8*)((BC) + bbase + ((nh)*2+nf)*1024 + sA0);     \
    bb[2 + nf] = *(const short8*)((BC) + bbase + ((nh)*2+nf)*1024 + sA1);     \
  }                                                                           \
} while (0)

#define CL16(mh, nh, bb) do {                                                 \
  __builtin_amdgcn_s_setprio(1);                                              \
  _Pragma("unroll")                                                           \
  for (int kk = 0; kk < 2; ++kk)                                              \
    _Pragma("unroll")                                                         \
    for (int mf = 0; mf < 4; ++mf)                                            \
      _Pragma("unroll")                                                       \
      for (int nf = 0; nf < 2; ++nf)                                          \
        acc[(mh)*4+mf][(nh)*2+nf] = __builtin_amdgcn_mfma_f32_16x16x32_bf16(  \
            aa[kk*4+mf], bb[kk*2+nf], acc[(mh)*4+mf][(nh)*2+nf], 0, 0, 0);    \
  __builtin_amdgcn_s_setprio(0);                                              \
} while (0)

#define BAR __builtin_amdgcn_s_barrier()

#define TILE(tt, TA, TB, SA2, SB1) do {                                       \
  const unsigned short* Ac = As + (TA) * ASL;                                 \
  const unsigned short* Bc = Bs + (TB) * BSL;                                 \
  BSTG((tt) + 1, SB1, 0); BBA(0, Ac); BBB(0, bb0, Bc);                        \
  BAR; CL16(0, 0, bb0); BAR;                                                  \
  BSTG((tt) + 1, SB1, 1); BBB(1, bb1, Bc);                                    \
  BAR; CL16(0, 1, bb1); BAR;                                                  \
  ASTG((tt) + 2, SA2, 0); BBA(1, Ac);                                         \
  BAR; CL16(1, 1, bb1); BAR;                                                  \
  ASTG((tt) + 2, SA2, 1); BBB(0, bb0, Bc);                                    \
  BAR; CL16(1, 0, bb0);                                                       \
  asm volatile("s_waitcnt vmcnt(4)" ::: "memory");                            \
  BAR;                                                                        \
} while (0)

  // prologue: A(0)->slot0, A(1)->slot1, B(0)->b0; full drain once
  ASTG(0, 0, 0); ASTG(0, 0, 1);
  ASTG(1, 1, 0); ASTG(1, 1, 1);
  BSTG(0, 0, 0); BSTG(0, 0, 1);
  asm volatile("s_waitcnt vmcnt(0)" ::: "memory");
  BAR;

  // tiles 0..29 (5 groups of 6 with compile-time slot pattern), then 30..35
  for (int k6 = 0; k6 < 30; k6 += 6) {
    TILE(k6 + 0, 0, 0, 2, 1);
    TILE(k6 + 1, 1, 1, 0, 0);
    TILE(k6 + 2, 2, 0, 1, 1);
    TILE(k6 + 3, 0, 1, 2, 0);
    TILE(k6 + 4, 1, 0, 0, 1);
    TILE(k6 + 5, 2, 1, 1, 0);
  }
  TILE(30, 0, 0, 2, 1);
  TILE(31, 1, 1, 0, 0);
  TILE(32, 2, 0, 1, 1);
  TILE(33, 0, 1, 2, 0);
  {  // tile 34: Ac=As[1], Bc=Bs[0]; stage B(35)->Bs[1]; drain all at end
    const unsigned short* Ac = As + 1 * ASL;
    const unsigned short* Bc = Bs + 0 * BSL;
    BSTG(35, 1, 0); BBA(0, Ac); BBB(0, bb0, Bc);
    BAR; CL16(0, 0, bb0); BAR;
    BSTG(35, 1, 1); BBB(1, bb1, Bc);
    BAR; CL16(0, 1, bb1); BAR;
    BBA(1, Ac);
    BAR; CL16(1, 1, bb1); BAR;
    BBB(0, bb0, Bc);
    BAR; CL16(1, 0, bb0);
    asm volatile("s_waitcnt vmcnt(0)" ::: "memory");
    BAR;
  }
  {  // tile 35: Ac=As[2], Bc=Bs[1]; pure compute
    const unsigned short* Ac = As + 2 * ASL;
    const unsigned short* Bc = Bs + 1 * BSL;
    BBA(0, Ac); BBB(0, bb0, Bc);
    BAR; CL16(0, 0, bb0); BAR;
    BBB(1, bb1, Bc);
    BAR; CL16(0, 1, bb1); BAR;
    BBA(1, Ac);
    BAR; CL16(1, 1, bb1); BAR;
    BBB(0, bb0, Bc);
    CL16(1, 0, bb0);
  }

  // epilogue: D col(px)=l&15, row(co)=(l>>4)*4+r
#pragma unroll
  for (int mf = 0; mf < 8; ++mf) {
    int cobase = wm * 128 + mf * 16 + hi4 * 4;
    const float4 bv = *(const float4*)(bias + cobase);
    float* op = out + ((size_t)n * CO + cobase) * HWp + p0 + wn * 64;
#pragma unroll
    for (int nf = 0; nf < 4; ++nf) {
      int w = nf * 16 + lc;
      f32x4 v = acc[mf][nf];
      op[w]                   = v[0] + bv.x;
      op[(size_t)HWp + w]     = v[1] + bv.y;
      op[(size_t)2 * HWp + w] = v[2] + bv.z;
      op[(size_t)3 * HWp + w] = v[3] + bv.w;
    }
  }
}

extern "C" void kernel_launch(void* const* d_in, const int* in_sizes, int n_in,
                              void* d_out, int out_size, void* d_ws, size_t ws_size,
                              hipStream_t stream) {
  const int* mask = (const int*)d_in[0];
  const float* ori = (const float*)d_in[1];
  const float* weight = (const float*)d_in[2];
  const float* bias = (const float*)d_in[3];
  float* out = (float*)d_out;

  unsigned short* xp = (unsigned short*)d_ws;          // padded NHWC bf16, 107.5 MB
  unsigned short* w2 = xp + XPAD_ELEMS;                // 1.2 MB [sh][co][ci]

  prep_all<<<NBORD + NPW + NPX, 256, 0, stream>>>(ori, mask, weight, xp, w2);
  sconv_gemm<<<800, 512, 0, stream>>>(xp, w2, bias, out);
}

// Round 17
// 305.922 us; speedup vs baseline: 1.3923x; 1.3923x over previous
//
#include <hip/hip_runtime.h>

typedef __attribute__((ext_vector_type(8))) short short8;
typedef __attribute__((ext_vector_type(4))) float f32x4;

#define B_    8
#define CI    256
#define CO    256
#define Hh    160
#define Ww    160
#define HP    162
#define WP    162
#define HWp   (Hh * Ww)                 // 25600
#define XPAD_ELEMS (B_ * HP * WP * CI)  // 53,747,712 bf16
#define W3_ELEMS   (9 * CI * CO)        // 589,824 bf16 (granule order)
#define NT    36                        // 4 ci-chunks x 9 shifts, BK=64
#define BSLOT (160 * 64)                // shorts per B slot: 160px x 64ci = 20KB

// fused prep grid partition
#define NBORD 644
#define NPW   2304                      // 589824 / 256
#define NPX   (B_ * Hh * 4 * 3)        // 15360

__device__ __forceinline__ unsigned short f2bf(float f) {
  unsigned int u = __float_as_uint(f);
  u += 0x7FFFu + ((u >> 16) & 1u);   // RNE
  return (unsigned short)(u >> 16);
}

// One launch: zero xp border | weight->w3 granules | ori*mask->xp packed NHWC bf16
// w3 granule layout (unchanged from r6-r16):
// g = shift*128 + cic*32 + qm*16 + kk*8 + wm*2 + mi ; elem = g*512 + l*8 + e
// co = qm*128 + wm*32 + mi*16 + (l&15) ; ci = cic*64 + kk*32 + (l>>4)*8 + e
__global__ void prep_all(const float* __restrict__ ori, const int* __restrict__ mask,
                         const float* __restrict__ w,
                         unsigned short* __restrict__ xp, unsigned short* __restrict__ w3) {
  __shared__ float tile[64][65];
  const int bid = blockIdx.x;
  const int t = threadIdx.x;

  if (bid < NBORD) {
    int g = bid * 256 + t;
    int pos = g >> 5;
    int c = (g & 31) << 3;
    int n = pos / 644;
    int p = pos - n * 644;
    int y, x;
    if (p < 324) { y = (p < 162) ? 0 : 161; x = (p < 162) ? p : p - 162; }
    else { int q = p - 324; y = 1 + (q >> 1); x = (q & 1) ? 161 : 0; }
    unsigned short* d = xp + (((size_t)(n * 162 + y)) * 162 + x) * 256 + c;
    *(uint4*)d = (uint4){0u, 0u, 0u, 0u};
    return;
  }
  if (bid < NBORD + NPW) {
    int i = (bid - NBORD) * 256 + t;
    int e = i & 7, l = (i >> 3) & 63, g = i >> 9;
    int mi = g & 1, wm = (g >> 1) & 3, kk = (g >> 3) & 1;
    int qm = (g >> 4) & 1, cic = (g >> 5) & 3, shift = g >> 7;
    int co = qm * 128 + wm * 32 + mi * 16 + (l & 15);
    int ci = cic * 64 + kk * 32 + (l >> 4) * 8 + e;
    w3[i] = f2bf(w[(co * 256 + ci) * 9 + shift]);
    return;
  }

  // prep_x: bid2 = ((n*160+h)*4+cit)*3+wt
  int bid2 = bid - (NBORD + NPW);
  int wt = bid2 % 3;
  int t1 = bid2 / 3;
  int cit = t1 & 3;
  int t2 = t1 >> 2;
  int h = t2 % Hh;
  int n = t2 / Hh;

  int wl = t & 63;
  int ww = wt * 64 + wl;
  bool valid = (ww < Ww);
  float m = 0.f;
  if (valid) m = (float)mask[(n * Hh + h) * Ww + ww];
  const float* src = ori + (((size_t)(n * CI + cit * 64) * Hh + h) * Ww + ww);
  int r0 = t >> 6;
#pragma unroll
  for (int k = 0; k < 16; ++k) {
    int ci_l = r0 * 16 + k;
    float v = 0.f;
    if (valid) v = src[(size_t)ci_l * HWp] * m;
    tile[ci_l][wl] = v;
  }
  __syncthreads();

  int wl2 = t >> 2;
  int wo = wt * 64 + wl2;
  if (wo < Ww) {
    int cseg = (t & 3) * 16;
    union { unsigned short u[8]; uint4 v; } p0, p1;
#pragma unroll
    for (int j = 0; j < 8; ++j) p0.u[j] = f2bf(tile[cseg + j][wl2]);
#pragma unroll
    for (int j = 0; j < 8; ++j) p1.u[j] = f2bf(tile[cseg + 8 + j][wl2]);
    unsigned short* dst = xp + ((size_t)((n * HP + h + 1) * WP) + (wo + 1)) * CI + cit * 64 + cseg;
    *(uint4*)dst = p0.v;
    *(uint4*)(dst + 8) = p1.v;
  }
}

__device__ __forceinline__ void gload16(const unsigned short* g, unsigned short* l) {
  __builtin_amdgcn_global_load_lds((const __attribute__((address_space(1))) void*)g,
                                   (__attribute__((address_space(3))) void*)l, 16, 0, 0);
}

// Implicit GEMM (r12 base — best measured) with trailing phase-barriers removed:
// per phase {issue VMEM -> 5 ds_read -> s_barrier -> setprio(1) -> 20 MFMA ->
// setprio(0)}; ONE tile-boundary barrier + ONE counted vmcnt(13) per tile.
// 5 barriers/tile vs r12's 8 — the trailing barriers were pure pacing; slot
// liveness is protected by the end-of-tile vmcnt+barrier (staging of slot s at
// tile t issues only after tile-(t-1)'s boundary barrier, by which time every
// read of s has completed into its MFMA cluster via compiler lgkm waits).
// A direct-to-reg split by kk half (aK0 refilled ph3-issue, aK1 ph4-end —
// hazard-free, in-order per wave). B: 3-slot 20KB LDS ring. Block 256thr/4
// waves = 256co x 160px (one image row), wave 64co x 160px, acc[4][10] f32x4.
// LDS 60KB, 2 blocks/CU. Grid 1280 = 8 img (XCD-owned) x 160 rows.
__global__ void __launch_bounds__(256, 2)
sconv_gemm(const unsigned short* __restrict__ xp, const unsigned short* __restrict__ w3,
           const float* __restrict__ bias, float* __restrict__ out) {
  __shared__ unsigned short Bs[3][BSLOT];   // 60KB

  const int bid = blockIdx.x;
  const int n = bid & 7;          // image per XCD
  const int h = bid >> 3;         // output row

  const int t = threadIdx.x;
  const int l = t & 63;
  const int wv = t >> 6;

  const int lr = l >> 3;
  const int swz8 = ((l & 7) ^ lr) << 3;   // proven source pre-swizzle (shorts)
  const int lc = l & 15, hi4 = l >> 4, lx7 = l & 7;
  const unsigned xrow = (unsigned)(n * HP + h);

  // stage lane offsets: call k covers px rows [k*32, k*32+32); wave wv rows +wv*8
  unsigned boff[5];
#pragma unroll
  for (int k = 0; k < 5; ++k)
    boff[k] = (unsigned)(k * 32 + wv * 8 + lr) * 256 + swz8;

  f32x4 acc[4][10];
#pragma unroll
  for (int j = 0; j < 4; ++j)
#pragma unroll
    for (int ni = 0; ni < 10; ++ni)
      acc[j][ni] = (f32x4){0.f, 0.f, 0.f, 0.f};

  short8 aK0[4], aK1[4], bb[5];

#define TPAR(ts, cic, sh, kh, kw)                                             \
  const int cic = ((ts) * 57) >> 9;                                           \
  const int sh = (ts) - cic * 9;                                              \
  const int kh = (sh * 11) >> 5;                                              \
  const int kw = sh - kh * 3;

  auto STG = [&](int ts, unsigned short* slot, int k) {
    TPAR(ts, cic, sh, kh, kw)
    (void)sh;
    const unsigned short* src = xp + ((size_t)(xrow + kh) * WP + kw) * 256 + (cic << 6) + boff[k];
    gload16(src, slot + (k * 32 + wv * 8) * 64);
  };

  auto AGH = [&](int ts, int kk, short8* dst) {
    TPAR(ts, cic, sh, kh, kw)
    (void)kh; (void)kw;
    const unsigned short* p = w3 +
        ((size_t)(sh * 128 + cic * 32 + (wv >> 1) * 16 + ((wv & 1) << 2) + kk * 8) << 9) + (l << 3);
#pragma unroll
    for (int j = 0; j < 4; ++j)
      dst[j] = *(const short8*)(p + (j << 9));
  };

#define BBR(slot, kk, nb) do {                                                \
  _Pragma("unroll")                                                           \
  for (int i = 0; i < 5; ++i)                                                 \
    bb[i] = *(const short8*)((slot) + (((nb) + i) * 16 + lc) * 64 +           \
                             (((((kk) << 2) + hi4) ^ lx7) << 3));             \
} while (0)

#define CL(AH, nb) do {                                                       \
  __builtin_amdgcn_s_setprio(1);                                              \
  _Pragma("unroll")                                                           \
  for (int j = 0; j < 4; ++j)                                                 \
    _Pragma("unroll")                                                         \
    for (int i = 0; i < 5; ++i)                                               \
      acc[j][(nb) + i] = __builtin_amdgcn_mfma_f32_16x16x32_bf16(             \
          AH[j], bb[i], acc[j][(nb) + i], 0, 0, 0);                           \
  __builtin_amdgcn_s_setprio(0);                                              \
} while (0)

  // phase WITHOUT trailing barrier: issues -> ds_reads -> barrier -> MFMA
#define PH_NB(slot, kk, AH, nb, ISSUES, ENDW) do {                            \
  ISSUES                                                                      \
  BBR(slot, kk, nb);                                                          \
  __builtin_amdgcn_s_barrier();                                               \
  CL(AH, nb);                                                                 \
  ENDW                                                                        \
} while (0)

  // final phase of a tile: trailing barrier = tile boundary
#define PH_B(slot, kk, AH, nb, ISSUES, ENDW) do {                             \
  PH_NB(slot, kk, AH, nb, ISSUES, ENDW);                                      \
  __builtin_amdgcn_s_barrier();                                               \
} while (0)

#define TILE(tt, sc, sn) do {                                                 \
  PH_NB(sc, 0, aK0, 0, { STG((tt) + 2, sn, 0); STG((tt) + 2, sn, 1); }, {});  \
  PH_NB(sc, 0, aK0, 5, { STG((tt) + 2, sn, 2); }, {});                        \
  PH_NB(sc, 1, aK1, 0, { AGH((tt) + 1, 0, aK0); STG((tt) + 2, sn, 3); }, {}); \
  PH_B(sc, 1, aK1, 5, { STG((tt) + 2, sn, 4); },                              \
     { AGH((tt) + 1, 1, aK1);                                                 \
       asm volatile("s_waitcnt vmcnt(13)" ::: "memory"); });                  \
} while (0)

  unsigned short* const s0 = &Bs[0][0];
  unsigned short* const s1 = &Bs[1][0];
  unsigned short* const s2 = &Bs[2][0];

  // prologue: stage tiles 0,1; load A(0); keep st(1)5 + A(0)8 = 13 in flight
  for (int k = 0; k < 5; ++k) STG(0, s0, k);
  for (int k = 0; k < 5; ++k) STG(1, s1, k);
  AGH(0, 0, aK0);
  AGH(0, 1, aK1);
  asm volatile("s_waitcnt vmcnt(13)" ::: "memory");
  __builtin_amdgcn_s_barrier();

  // tiles 0..33 staged; 34,35 peeled (no staging)
  for (int t3 = 0; t3 < 33; t3 += 3) {
    TILE(t3 + 0, s0, s2);
    TILE(t3 + 1, s1, s0);
    TILE(t3 + 2, s2, s1);
  }
  TILE(33, s0, s2);
  // tile 34 (slot s1): A(35) halves at the hazard-free points
  PH_NB(s1, 0, aK0, 0, {}, {});
  PH_NB(s1, 0, aK0, 5, {}, {});
  PH_NB(s1, 1, aK1, 0, { AGH(35, 0, aK0); }, {});
  PH_B(s1, 1, aK1, 5, {},
     { AGH(35, 1, aK1);
       asm volatile("s_waitcnt vmcnt(8)" ::: "memory"); });   // STG(35) drained
  // tile 35 (slot s2): final, no trailing sync
  PH_NB(s2, 0, aK0, 0, {}, {});
  PH_NB(s2, 0, aK0, 5, {}, {});
  PH_NB(s2, 1, aK1, 0, {}, {});
  {
    BBR(s2, 1, 5);
    CL(aK1, 5);
  }

  // epilogue: D col(px)=l&15, row(co)=(l>>4)*4+r; wave covers co [wv*64, wv*64+64)
#pragma unroll
  for (int j = 0; j < 4; ++j) {
    int cobase = wv * 64 + j * 16 + hi4 * 4;
    const float4 bv = *(const float4*)(bias + cobase);
    float* op = out + (((size_t)n * CO + cobase) * Hh + h) * Ww;
#pragma unroll
    for (int ni = 0; ni < 10; ++ni) {
      int w = ni * 16 + lc;
      f32x4 v = acc[j][ni];
      op[w]                   = v[0] + bv.x;
      op[(size_t)HWp + w]     = v[1] + bv.y;
      op[(size_t)2 * HWp + w] = v[2] + bv.z;
      op[(size_t)3 * HWp + w] = v[3] + bv.w;
    }
  }
}

extern "C" void kernel_launch(void* const* d_in, const int* in_sizes, int n_in,
                              void* d_out, int out_size, void* d_ws, size_t ws_size,
                              hipStream_t stream) {
  const int* mask = (const int*)d_in[0];
  const float* ori = (const float*)d_in[1];
  const float* weight = (const float*)d_in[2];
  const float* bias = (const float*)d_in[3];
  float* out = (float*)d_out;

  unsigned short* xp = (unsigned short*)d_ws;          // padded NHWC bf16, 107.5 MB
  unsigned short* w3 = xp + XPAD_ELEMS;                // 1.2 MB granule-ordered weights

  prep_all<<<NBORD + NPW + NPX, 256, 0, stream>>>(ori, mask, weight, xp, w3);
  sconv_gemm<<<1280, 256, 0, stream>>>(xp, w3, bias, out);
}